// Round 1
// baseline (7057.300 us; speedup 1.0000x reference)
//
#include <hip/hip_runtime.h>
#include <math.h>

#define GRPO_BETA 0.1f

constexpr int BM = 64;     // rows per block tile
constexpr int BN = 256;    // vocab cols per block tile
constexpr int BK = 16;     // k-tile
constexpr int LDAP = BM + 4;  // 68: keeps float4 (16B) alignment, spreads banks

// NaN-safe exp for combine steps: args are expected <= 0; fminf(NaN,0)=0.
__device__ __forceinline__ float sexp_fast(float a) { return __expf(fminf(a, 0.f)); }
__device__ __forceinline__ float sexp(float a)      { return expf(fminf(a, 0.f)); }

// ---------------------------------------------------------------------------
// Kernel 1: tiled f32 GEMM (logits = A[M,K] x W[V,K]^T) fused with per-row,
// per-vocab-chunk reductions. POLICY=true also tracks argmax and sum(logits).
// Record per (row, chunk): POLICY -> float4{max, sumexp, sum, bitcast(argmax)}
//                          else   -> float2{max, sumexp}
// grid = (ceil(M/BM), NC), block = 256
// ---------------------------------------------------------------------------
template <bool POLICY>
__global__ __launch_bounds__(256)
void gemm_reduce_kernel(const float* __restrict__ A,
                        const float* __restrict__ W,
                        float* __restrict__ part,
                        int M, int K, int V, int NC, int NL)
{
  __shared__ __align__(16) float lds_a[BK * LDAP];
  __shared__ __align__(16) float lds_w[BK * BN];

  const int tid  = threadIdx.x;
  const int row0 = blockIdx.x * BM;
  const int tcol = tid & 31;   // 0..31 -> col groups
  const int trow = tid >> 5;   // 0..7  -> row groups
  const int r0   = trow * 8;

  const int a_r = tid >> 2;         // 0..63 row for A staging
  const int a_k = (tid & 3) * 4;    // k sub-offset

  // running per-row records across sub-tiles
  float rm[8], rse[8], rsum[8];
  int   ri[8];
#pragma unroll
  for (int i = 0; i < 8; ++i) { rm[i] = -INFINITY; rse[i] = 0.f; rsum[i] = 0.f; ri[i] = 0x7fffffff; }

  const int arow = min(row0 + a_r, M - 1);
  const float* abase = A + (size_t)arow * K;

  for (int sub = 0; sub < NL; ++sub) {
    const int v0 = (blockIdx.y * NL + sub) * BN;
    if (v0 >= V) break;

    float acc[8][8];
#pragma unroll
    for (int i = 0; i < 8; ++i)
#pragma unroll
      for (int j = 0; j < 8; ++j) acc[i][j] = 0.f;

    const int wrow = min(v0 + tid, V - 1);
    const float* wbase = W + (size_t)wrow * K;

    for (int k0 = 0; k0 < K; k0 += BK) {
      __syncthreads();  // protect LDS from previous iteration's readers
      float4 av = *reinterpret_cast<const float4*>(abase + k0 + a_k);
      lds_a[(a_k + 0) * LDAP + a_r] = av.x;
      lds_a[(a_k + 1) * LDAP + a_r] = av.y;
      lds_a[(a_k + 2) * LDAP + a_r] = av.z;
      lds_a[(a_k + 3) * LDAP + a_r] = av.w;
#pragma unroll
      for (int q = 0; q < 4; ++q) {
        float4 wv = *reinterpret_cast<const float4*>(wbase + k0 + q * 4);
        lds_w[(q * 4 + 0) * BN + tid] = wv.x;
        lds_w[(q * 4 + 1) * BN + tid] = wv.y;
        lds_w[(q * 4 + 2) * BN + tid] = wv.z;
        lds_w[(q * 4 + 3) * BN + tid] = wv.w;
      }
      __syncthreads();
#pragma unroll
      for (int k = 0; k < BK; ++k) {
        float a[8], w[8];
        float4 a0 = *reinterpret_cast<const float4*>(&lds_a[k * LDAP + r0]);
        float4 a1 = *reinterpret_cast<const float4*>(&lds_a[k * LDAP + r0 + 4]);
        a[0] = a0.x; a[1] = a0.y; a[2] = a0.z; a[3] = a0.w;
        a[4] = a1.x; a[5] = a1.y; a[6] = a1.z; a[7] = a1.w;
#pragma unroll
        for (int p = 0; p < 4; ++p) {
          float2 wv = *reinterpret_cast<const float2*>(&lds_w[k * BN + 2 * tcol + 64 * p]);
          w[2 * p] = wv.x; w[2 * p + 1] = wv.y;
        }
#pragma unroll
        for (int i = 0; i < 8; ++i)
#pragma unroll
          for (int j = 0; j < 8; ++j)
            acc[i][j] = fmaf(a[i], w[j], acc[i][j]);
      }
    }

    // ---- epilogue: per-row reduction over this 256-col sub-tile ----
#pragma unroll
    for (int i = 0; i < 8; ++i) {
      float lm = -INFINITY; int li = 0x7fffffff; float lsum = 0.f;
#pragma unroll
      for (int j = 0; j < 8; ++j) {           // j ascending == col ascending
        int c = 2 * tcol + 64 * (j >> 1) + (j & 1);
        int v = v0 + c;
        float x = acc[i][j];
        if (v < V) {
          lsum += x;
          if (x > lm) { lm = x; li = v; }
        }
      }
      float lse_ = 0.f;
#pragma unroll
      for (int j = 0; j < 8; ++j) {
        int v = v0 + 2 * tcol + 64 * (j >> 1) + (j & 1);
        if (v < V) lse_ += __expf(acc[i][j] - lm);
      }
      // cross-lane reduce over the 32 tcols sharing these rows
      float cm = lm; int ci = li; float cse = lse_, csum = lsum;
#pragma unroll
      for (int d = 1; d < 32; d <<= 1) {
        float om  = __shfl_xor(cm, d);
        int   oi  = __shfl_xor(ci, d);
        float ose = __shfl_xor(cse, d);
        float osm = __shfl_xor(csum, d);
        float nm = fmaxf(cm, om);
        cse = cse * sexp_fast(cm - nm) + ose * sexp_fast(om - nm);
        csum += osm;
        if (om > cm || (om == cm && oi < ci)) ci = oi;
        cm = nm;
      }
      // merge into running record
      float nm = fmaxf(rm[i], cm);
      rse[i] = rse[i] * sexp_fast(rm[i] - nm) + cse * sexp_fast(cm - nm);
      rsum[i] += csum;
      if (cm > rm[i] || (cm == rm[i] && ci < ri[i])) ri[i] = ci;
      rm[i] = nm;
    }
  }

  const int chunk = blockIdx.y;
  if (tcol == 0) {
#pragma unroll
    for (int i = 0; i < 8; ++i) {
      int row = row0 + r0 + i;
      if (row < M) {
        if (POLICY) {
          reinterpret_cast<float4*>(part)[(size_t)row * NC + chunk] =
              make_float4(rm[i], rse[i], rsum[i], __int_as_float(ri[i]));
        } else {
          reinterpret_cast<float2*>(part)[(size_t)row * NC + chunk] =
              make_float2(rm[i], rse[i]);
        }
      }
    }
  }
}

// ---------------------------------------------------------------------------
// Kernel 2: per-row combine of chunk partials + gathered ref dot.
// Writes rowtab[row] = {tok_lp, kl, mean_v(log_probs_row), 0}
// grid = (M), block = 256
// ---------------------------------------------------------------------------
__global__ __launch_bounds__(256)
void combine_kernel(const float4* __restrict__ partP,
                    const float2* __restrict__ partR,
                    const float* __restrict__ refA,
                    const float* __restrict__ refW,
                    float4* __restrict__ rowtab,
                    int M, int K, int V, int NC)
{
  const int row = blockIdx.x;
  const int tid = threadIdx.x;

  __shared__ float redf[256];
  __shared__ int   redi[256];
  __shared__ float s_M, s_SE, s_SUM, s_Mr, s_SEr, s_dot;
  __shared__ int   s_idx;

  // ---- policy: thread-local combine
  float m = -INFINITY, se = 0.f, sm = 0.f; int idx = 0x7fffffff;
  for (int i = tid; i < NC; i += 256) {
    float4 p = partP[(size_t)row * NC + i];
    int pi = __float_as_int(p.w);
    float nm = fmaxf(m, p.x);
    se = se * sexp(m - nm) + p.y * sexp(p.x - nm);
    if (p.x > m || (p.x == m && pi < idx)) idx = pi;
    m = nm;
    sm += p.z;
  }
  // block max+argmax
  redf[tid] = m; redi[tid] = idx;
  __syncthreads();
  for (int s = 128; s > 0; s >>= 1) {
    if (tid < s) {
      float om = redf[tid + s]; int oi = redi[tid + s];
      if (om > redf[tid] || (om == redf[tid] && oi < redi[tid])) { redf[tid] = om; redi[tid] = oi; }
    }
    __syncthreads();
  }
  if (tid == 0) { s_M = redf[0]; s_idx = redi[0]; }
  __syncthreads();
  const float Mp = s_M; const int chosen = s_idx;

  // block sum of rescaled sumexp
  float contrib = se * sexp(m - Mp);
  __syncthreads();
  redf[tid] = contrib; __syncthreads();
  for (int s = 128; s > 0; s >>= 1) { if (tid < s) redf[tid] += redf[tid + s]; __syncthreads(); }
  if (tid == 0) s_SE = redf[0];
  __syncthreads();
  redf[tid] = sm; __syncthreads();
  for (int s = 128; s > 0; s >>= 1) { if (tid < s) redf[tid] += redf[tid + s]; __syncthreads(); }
  if (tid == 0) s_SUM = redf[0];
  __syncthreads();

  // ---- ref: max + sumexp
  float mr = -INFINITY, ser = 0.f;
  for (int i = tid; i < NC; i += 256) {
    float2 p = partR[(size_t)row * NC + i];
    float nm = fmaxf(mr, p.x);
    ser = ser * sexp(mr - nm) + p.y * sexp(p.x - nm);
    mr = nm;
  }
  redf[tid] = mr; __syncthreads();
  for (int s = 128; s > 0; s >>= 1) { if (tid < s) redf[tid] = fmaxf(redf[tid], redf[tid + s]); __syncthreads(); }
  if (tid == 0) s_Mr = redf[0];
  __syncthreads();
  const float Mr = s_Mr;
  float contribr = ser * sexp(mr - Mr);
  __syncthreads();
  redf[tid] = contribr; __syncthreads();
  for (int s = 128; s > 0; s >>= 1) { if (tid < s) redf[tid] += redf[tid + s]; __syncthreads(); }
  if (tid == 0) s_SEr = redf[0];
  __syncthreads();

  // ---- gathered dot: ref_input[row] . ref_weight[chosen]
  float dp = 0.f;
  const float* ar = refA + (size_t)row * K;
  const float* wr = refW + (size_t)chosen * K;
  for (int j = tid * 4; j < K; j += 256 * 4) {
    float4 x = *reinterpret_cast<const float4*>(ar + j);
    float4 y = *reinterpret_cast<const float4*>(wr + j);
    dp = fmaf(x.x, y.x, dp);
    dp = fmaf(x.y, y.y, dp);
    dp = fmaf(x.z, y.z, dp);
    dp = fmaf(x.w, y.w, dp);
  }
  __syncthreads();
  redf[tid] = dp; __syncthreads();
  for (int s = 128; s > 0; s >>= 1) { if (tid < s) redf[tid] += redf[tid + s]; __syncthreads(); }
  if (tid == 0) s_dot = redf[0];
  __syncthreads();

  if (tid == 0) {
    float lse     = Mp + logf(s_SE);
    float tok     = Mp - lse;
    float ref_lse = Mr + logf(s_SEr);
    float ref_tok = s_dot - ref_lse;
    float d  = ref_tok - tok;
    float kl = expm1f(d) - d;          // exp(d) - d - 1
    float rm3 = s_SUM / (float)V - lse; // mean over V of (logit - lse)
    rowtab[row] = make_float4(tok, kl, rm3, 0.f);
  }
}

// ---------------------------------------------------------------------------
// Kernel 3: final reduction over rows -> 5 scalar outputs.
// grid = (1), block = 256
// ---------------------------------------------------------------------------
__global__ __launch_bounds__(256)
void final_kernel(const float4* __restrict__ rowtab,
                  const float* __restrict__ mask,
                  const float* __restrict__ rewards,
                  float* __restrict__ out,
                  int M, int B, int T)
{
  const int tid = threadIdx.x;
  __shared__ float redf[256];
  __shared__ float s_mean, s_m3, s_var;
  __shared__ float s_kl[16], s_cnt[16];

  // pass 1: sum(tok_lp), sum(row m3)
  float st = 0.f, sm3 = 0.f;
  for (int r = tid; r < M; r += 256) {
    float4 v = rowtab[r];
    st += v.x; sm3 += v.z;
  }
  redf[tid] = st; __syncthreads();
  for (int s = 128; s > 0; s >>= 1) { if (tid < s) redf[tid] += redf[tid + s]; __syncthreads(); }
  if (tid == 0) s_mean = redf[0] / (float)M;
  __syncthreads();
  redf[tid] = sm3; __syncthreads();
  for (int s = 128; s > 0; s >>= 1) { if (tid < s) redf[tid] += redf[tid + s]; __syncthreads(); }
  if (tid == 0) s_m3 = redf[0] / (float)M;
  __syncthreads();

  // pass 2: centered variance of tok_lp (two-pass avoids cancellation)
  const float mean = s_mean;
  float sv = 0.f;
  for (int r = tid; r < M; r += 256) { float d = rowtab[r].x - mean; sv = fmaf(d, d, sv); }
  __syncthreads();
  redf[tid] = sv; __syncthreads();
  for (int s = 128; s > 0; s >>= 1) { if (tid < s) redf[tid] += redf[tid + s]; __syncthreads(); }
  if (tid == 0) s_var = redf[0];
  __syncthreads();

  // pass 3: per-sequence masked kl sum and mask count
  const int nb = B < 16 ? B : 16;
  for (int b = 0; b < nb; ++b) {
    float lk = 0.f, lc = 0.f;
    for (int t = tid; t < T; t += 256) {
      int r = b * T + t;
      float mk = mask[r];
      lk = fmaf(rowtab[r].y, mk, lk);
      lc += mk;
    }
    __syncthreads();
    redf[tid] = lk; __syncthreads();
    for (int s = 128; s > 0; s >>= 1) { if (tid < s) redf[tid] += redf[tid + s]; __syncthreads(); }
    if (tid == 0) s_kl[b] = redf[0];
    __syncthreads();
    redf[tid] = lc; __syncthreads();
    for (int s = 128; s > 0; s >>= 1) { if (tid < s) redf[tid] += redf[tid + s]; __syncthreads(); }
    if (tid == 0) s_cnt[b] = redf[0];
    __syncthreads();
  }

  if (tid == 0) {
    float rmean = 0.f;
    for (int b = 0; b < B; ++b) rmean += rewards[b];
    rmean /= (float)B;
    float rv = 0.f;
    for (int b = 0; b < B; ++b) { float d = rewards[b] - rmean; rv += d * d; }
    float rstd = sqrtf(rv / (float)(B > 1 ? B - 1 : 1));

    float loss = 0.f, m4n = 0.f, m4d = 0.f;
    for (int b = 0; b < nb; ++b) {
      float adv  = (rewards[b] - rmean) / (rstd + 1e-8f);
      float cnt  = s_cnt[b];
      float seql = fmaxf(cnt, 1.0f);
      loss += (-adv * cnt + GRPO_BETA * s_kl[b]) / seql;
      m4n += s_kl[b];
      m4d += cnt;
    }
    loss /= (float)B;

    out[0] = loss;
    out[1] = s_mean;                              // tok_lp.mean()
    out[2] = sqrtf(s_var / (float)(M - 1));       // std(tok_lp, ddof=1)
    out[3] = s_m3;                                // log_probs.mean()
    out[4] = m4n / m4d;                           // kl metric
  }
}

// ---------------------------------------------------------------------------
extern "C" void kernel_launch(void* const* d_in, const int* in_sizes, int n_in,
                              void* d_out, int out_size, void* d_ws, size_t ws_size,
                              hipStream_t stream)
{
  if (n_in < 6) return;
  const float* A       = (const float*)d_in[0];
  const float* W       = (const float*)d_in[1];
  const float* mask    = (const float*)d_in[2];
  const float* rewards = (const float*)d_in[3];
  const float* rA      = (const float*)d_in[4];
  const float* rW      = (const float*)d_in[5];

  const int M = in_sizes[2];            // B*T
  const int B = in_sizes[3];
  const int T = M / B;
  const int K = in_sizes[0] / M;        // H
  const int V = in_sizes[1] / K;

  // pick NL (vocab sub-tiles per block) so partials fit in ws
  int NL = 1;
  auto need = [&](int nl) -> size_t {
    int nc = (V + BN * nl - 1) / (BN * nl);
    return (size_t)M * nc * 16 + (size_t)M * nc * 8 + (size_t)M * 16;
  };
  while (need(NL) > ws_size && NL < 1024) NL <<= 1;
  const int NC = (V + BN * NL - 1) / (BN * NL);

  float* partP  = (float*)d_ws;                    // M*NC float4
  float* partR  = partP + (size_t)M * NC * 4;      // M*NC float2
  float* rowtab = partR + (size_t)M * NC * 2;      // M float4

  dim3 g1((M + BM - 1) / BM, NC), b1(256);
  gemm_reduce_kernel<true ><<<g1, b1, 0, stream>>>(A,  W,  partP, M, K, V, NC, NL);
  gemm_reduce_kernel<false><<<g1, b1, 0, stream>>>(rA, rW, partR, M, K, V, NC, NL);
  combine_kernel<<<dim3(M), dim3(256), 0, stream>>>(
      (const float4*)partP, (const float2*)partR, rA, rW, (float4*)rowtab, M, K, V, NC);
  final_kernel<<<dim3(1), dim3(256), 0, stream>>>(
      (const float4*)rowtab, mask, rewards, (float*)d_out, M, B, T);
}

// Round 2
// 2741.653 us; speedup vs baseline: 2.5741x; 2.5741x over previous
//
#include <hip/hip_runtime.h>
#include <math.h>

#define GRPO_BETA 0.1f

constexpr int BM = 128;    // rows per block tile
constexpr int BN = 256;    // vocab cols per block tile (chunk width)
constexpr int BK = 64;     // k-tile

typedef __attribute__((ext_vector_type(4))) float   f32x4;
typedef __attribute__((ext_vector_type(8))) __bf16  bf16x8;
typedef __attribute__((ext_vector_type(4))) __bf16  bf16x4;

// NaN-safe exp for lse merges: args expected <= 0; fminf(NaN,0)=0.
__device__ __forceinline__ float sexp_fast(float a) { return __expf(fminf(a, 0.f)); }
__device__ __forceinline__ float sexp(float a)      { return expf(fminf(a, 0.f)); }

__device__ __forceinline__ bf16x4 cvt4(float4 v) {
  bf16x4 r;
  r[0] = (__bf16)v.x; r[1] = (__bf16)v.y; r[2] = (__bf16)v.z; r[3] = (__bf16)v.w;
  return r;
}

// ---------------------------------------------------------------------------
// Kernel 1: bf16-MFMA GEMM (logits = A[M,K] x W[V,K]^T), f32 inputs converted
// in-kernel, fused per-row per-256-col-chunk reductions.
// Record per (row, chunk): POLICY -> float4{max, sumexp, sum, bitcast(argmax)}
//                          else   -> float2{max, sumexp}
// grid = (M/BM, NC), block = 512 (8 waves: 2 M x 4 N, wave tile 64x64)
// ---------------------------------------------------------------------------
template <bool POLICY>
__global__ __launch_bounds__(512)
void mfma_gemm_reduce(const float* __restrict__ A,
                      const float* __restrict__ W,
                      float* __restrict__ part,
                      int M, int K, int V, int NC, int NL)
{
  // LDS tiles, bf16, row-major with 128-byte rows, XOR-swizzled:
  // byte addr = row*128 + (off ^ ((row&7)<<4))
  __shared__ __align__(16) unsigned short lds_a[BM * BK];   // 16 KB
  __shared__ __align__(16) unsigned short lds_w[BN * BK];   // 32 KB
  __shared__ __align__(16) float4 lds_red[BM * 4];          // [row][wn], 8 KB

  const int tid  = threadIdx.x;
  const int lane = tid & 63;
  const int wave = tid >> 6;      // 0..7
  const int wm   = wave >> 2;     // 0..1  (M half)
  const int wn   = wave & 3;      // 0..3  (N quarter)
  const int l15  = lane & 15;
  const int q    = lane >> 4;     // 0..3
  const int swz  = (lane & 7) << 4;

  const int row0  = blockIdx.x * BM;
  const int chunk = blockIdx.y;

  // ---- staging maps (thread t covers 16B of f32 per assigned row) ----
  const int t15 = tid & 15;       // k sub-offset: floats [t15*4 .. t15*4+3]
  const int tr  = tid >> 4;       // 0..31
  const int wswz = (t15 * 8) ^ ((tr & 7) << 4);  // byte off within LDS row

  const float* pa[4];
  int la[4];
#pragma unroll
  for (int i = 0; i < 4; ++i) {
    const int r = tr + 32 * i;                       // 0..127
    const int arow = min(row0 + r, M - 1);
    pa[i] = A + (size_t)arow * K + t15 * 4;
    la[i] = r * 128 + wswz;
  }
  int lw[8];
#pragma unroll
  for (int i = 0; i < 8; ++i) {
    const int c = tr + 32 * i;                       // 0..255
    lw[i] = c * 128 + wswz;
  }

  // running per-row records (threads 0..127 own local row = tid)
  float rm = -INFINITY, rse = 0.f, rsum = 0.f;
  int   ridx = 0x7fffffff;

  for (int sub = 0; sub < NL; ++sub) {
    const int v0 = (chunk * NL + sub) * BN;
    if (v0 >= V) break;

    const float* pw[8];
#pragma unroll
    for (int i = 0; i < 8; ++i) {
      const int wrow = min(v0 + tr + 32 * i, V - 1);
      pw[i] = W + (size_t)wrow * K + t15 * 4;
    }

    f32x4 acc[4][4];
#pragma unroll
    for (int i = 0; i < 4; ++i)
#pragma unroll
      for (int j = 0; j < 4; ++j) acc[i][j] = (f32x4){0.f, 0.f, 0.f, 0.f};

    for (int k0 = 0; k0 < K; k0 += BK) {
      float4 ar[4], wr[8];
#pragma unroll
      for (int i = 0; i < 4; ++i) ar[i] = *reinterpret_cast<const float4*>(pa[i] + k0);
#pragma unroll
      for (int i = 0; i < 8; ++i) wr[i] = *reinterpret_cast<const float4*>(pw[i] + k0);

      __syncthreads();  // prev iteration's readers done
#pragma unroll
      for (int i = 0; i < 4; ++i)
        *reinterpret_cast<bf16x4*>(reinterpret_cast<char*>(lds_a) + la[i]) = cvt4(ar[i]);
#pragma unroll
      for (int i = 0; i < 8; ++i)
        *reinterpret_cast<bf16x4*>(reinterpret_cast<char*>(lds_w) + lw[i]) = cvt4(wr[i]);
      __syncthreads();

#pragma unroll
      for (int kk = 0; kk < 2; ++kk) {
        const int o = ((kk * 64) | (q * 16)) ^ swz;
        bf16x8 afr[4], wfr[4];
#pragma unroll
        for (int fm = 0; fm < 4; ++fm)
          afr[fm] = *reinterpret_cast<const bf16x8*>(
              reinterpret_cast<const char*>(lds_a) + (wm * 64 + fm * 16 + l15) * 128 + o);
#pragma unroll
        for (int fn = 0; fn < 4; ++fn)
          wfr[fn] = *reinterpret_cast<const bf16x8*>(
              reinterpret_cast<const char*>(lds_w) + (wn * 64 + fn * 16 + l15) * 128 + o);
#pragma unroll
        for (int fm = 0; fm < 4; ++fm)
#pragma unroll
          for (int fn = 0; fn < 4; ++fn)
            acc[fm][fn] = __builtin_amdgcn_mfma_f32_16x16x32_bf16(
                afr[fm], wfr[fn], acc[fm][fn], 0, 0, 0);
      }
    }

    // ---- fused epilogue: per-row reduction over this 256-col sub-tile ----
    // C/D layout: col = lane&15, row = (lane>>4)*4 + reg  [verified m89/m91]
#pragma unroll
    for (int fm = 0; fm < 4; ++fm) {
#pragma unroll
      for (int reg = 0; reg < 4; ++reg) {
        float lm = -INFINITY; int li = 0x7fffffff; float lsum = 0.f;
#pragma unroll
        for (int fn = 0; fn < 4; ++fn) {          // fn ascending == col ascending
          const int v = v0 + wn * 64 + fn * 16 + l15;
          const float x = acc[fm][fn][reg];
          if (v < V) {
            lsum += x;
            if (x > lm) { lm = x; li = v; }
          }
        }
        float lse = 0.f;
#pragma unroll
        for (int fn = 0; fn < 4; ++fn) {
          const int v = v0 + wn * 64 + fn * 16 + l15;
          if (v < V) lse += __expf(acc[fm][fn][reg] - lm);
        }
        // reduce across the 16 lanes sharing this row (xor d<16 stays in group)
#pragma unroll
        for (int d = 1; d < 16; d <<= 1) {
          const float om  = __shfl_xor(lm, d);
          const int   oi  = __shfl_xor(li, d);
          const float ose = __shfl_xor(lse, d);
          const float osm = __shfl_xor(lsum, d);
          const float nm  = fmaxf(lm, om);
          lse = lse * sexp_fast(lm - nm) + ose * sexp_fast(om - nm);
          lsum += osm;
          if (om > lm || (om == lm && oi < li)) li = oi;
          lm = nm;
        }
        if (l15 == 0) {
          const int row = wm * 64 + fm * 16 + q * 4 + reg;
          lds_red[row * 4 + wn] = make_float4(lm, lse, lsum, __int_as_float(li));
        }
      }
    }
    __syncthreads();

    if (tid < BM) {
      float4 p = lds_red[tid * 4];
      float m = p.x, se = p.y, sm = p.z; int idx = __float_as_int(p.w);
#pragma unroll
      for (int j = 1; j < 4; ++j) {
        const float4 t = lds_red[tid * 4 + j];
        const int ti = __float_as_int(t.w);
        const float nm = fmaxf(m, t.x);
        se = se * sexp_fast(m - nm) + t.y * sexp_fast(t.x - nm);
        sm += t.z;
        if (t.x > m || (t.x == m && ti < idx)) idx = ti;
        m = nm;
      }
      const float nm = fmaxf(rm, m);
      rse = rse * sexp_fast(rm - nm) + se * sexp_fast(m - nm);
      rsum += sm;
      if (m > rm || (m == rm && idx < ridx)) ridx = idx;
      rm = nm;
    }
    // next sub's first __syncthreads orders these reads before LDS reuse
  }

  if (tid < BM) {
    const int row = row0 + tid;
    if (row < M) {
      if (POLICY) {
        reinterpret_cast<float4*>(part)[(size_t)row * NC + chunk] =
            make_float4(rm, rse, rsum, __int_as_float(ridx));
      } else {
        reinterpret_cast<float2*>(part)[(size_t)row * NC + chunk] =
            make_float2(rm, rse);
      }
    }
  }
}

// ---------------------------------------------------------------------------
// Kernel 2: per-row combine of chunk partials + gathered ref dot (f32 exact).
// Writes rowtab[row] = {tok_lp, kl, mean_v(log_probs_row), 0}
// grid = (M), block = 256
// ---------------------------------------------------------------------------
__global__ __launch_bounds__(256)
void combine_kernel(const float4* __restrict__ partP,
                    const float2* __restrict__ partR,
                    const float* __restrict__ refA,
                    const float* __restrict__ refW,
                    float4* __restrict__ rowtab,
                    int M, int K, int V, int NC)
{
  const int row = blockIdx.x;
  const int tid = threadIdx.x;

  __shared__ float redf[256];
  __shared__ int   redi[256];
  __shared__ float s_M, s_SE, s_SUM, s_Mr, s_SEr, s_dot;
  __shared__ int   s_idx;

  float m = -INFINITY, se = 0.f, sm = 0.f; int idx = 0x7fffffff;
  for (int i = tid; i < NC; i += 256) {
    float4 p = partP[(size_t)row * NC + i];
    int pi = __float_as_int(p.w);
    float nm = fmaxf(m, p.x);
    se = se * sexp(m - nm) + p.y * sexp(p.x - nm);
    if (p.x > m || (p.x == m && pi < idx)) idx = pi;
    m = nm;
    sm += p.z;
  }
  redf[tid] = m; redi[tid] = idx;
  __syncthreads();
  for (int s = 128; s > 0; s >>= 1) {
    if (tid < s) {
      float om = redf[tid + s]; int oi = redi[tid + s];
      if (om > redf[tid] || (om == redf[tid] && oi < redi[tid])) { redf[tid] = om; redi[tid] = oi; }
    }
    __syncthreads();
  }
  if (tid == 0) { s_M = redf[0]; s_idx = redi[0]; }
  __syncthreads();
  const float Mp = s_M; const int chosen = s_idx;

  float contrib = se * sexp(m - Mp);
  __syncthreads();
  redf[tid] = contrib; __syncthreads();
  for (int s = 128; s > 0; s >>= 1) { if (tid < s) redf[tid] += redf[tid + s]; __syncthreads(); }
  if (tid == 0) s_SE = redf[0];
  __syncthreads();
  redf[tid] = sm; __syncthreads();
  for (int s = 128; s > 0; s >>= 1) { if (tid < s) redf[tid] += redf[tid + s]; __syncthreads(); }
  if (tid == 0) s_SUM = redf[0];
  __syncthreads();

  float mr = -INFINITY, ser = 0.f;
  for (int i = tid; i < NC; i += 256) {
    float2 p = partR[(size_t)row * NC + i];
    float nm = fmaxf(mr, p.x);
    ser = ser * sexp(mr - nm) + p.y * sexp(p.x - nm);
    mr = nm;
  }
  redf[tid] = mr; __syncthreads();
  for (int s = 128; s > 0; s >>= 1) { if (tid < s) redf[tid] = fmaxf(redf[tid], redf[tid + s]); __syncthreads(); }
  if (tid == 0) s_Mr = redf[0];
  __syncthreads();
  const float Mr = s_Mr;
  float contribr = ser * sexp(mr - Mr);
  __syncthreads();
  redf[tid] = contribr; __syncthreads();
  for (int s = 128; s > 0; s >>= 1) { if (tid < s) redf[tid] += redf[tid + s]; __syncthreads(); }
  if (tid == 0) s_SEr = redf[0];
  __syncthreads();

  float dp = 0.f;
  const float* ar = refA + (size_t)row * K;
  const float* wr = refW + (size_t)chosen * K;
  for (int j = tid * 4; j < K; j += 256 * 4) {
    float4 x = *reinterpret_cast<const float4*>(ar + j);
    float4 y = *reinterpret_cast<const float4*>(wr + j);
    dp = fmaf(x.x, y.x, dp);
    dp = fmaf(x.y, y.y, dp);
    dp = fmaf(x.z, y.z, dp);
    dp = fmaf(x.w, y.w, dp);
  }
  __syncthreads();
  redf[tid] = dp; __syncthreads();
  for (int s = 128; s > 0; s >>= 1) { if (tid < s) redf[tid] += redf[tid + s]; __syncthreads(); }
  if (tid == 0) s_dot = redf[0];
  __syncthreads();

  if (tid == 0) {
    float lse     = Mp + logf(s_SE);
    float tok     = Mp - lse;
    float ref_lse = Mr + logf(s_SEr);
    float ref_tok = s_dot - ref_lse;
    float d  = ref_tok - tok;
    float kl = expm1f(d) - d;
    float rm3 = s_SUM / (float)V - lse;
    rowtab[row] = make_float4(tok, kl, rm3, 0.f);
  }
}

// ---------------------------------------------------------------------------
// Kernel 3: final reduction over rows -> 5 scalar outputs. grid=(1), block=256
// ---------------------------------------------------------------------------
__global__ __launch_bounds__(256)
void final_kernel(const float4* __restrict__ rowtab,
                  const float* __restrict__ mask,
                  const float* __restrict__ rewards,
                  float* __restrict__ out,
                  int M, int B, int T)
{
  const int tid = threadIdx.x;
  __shared__ float redf[256];
  __shared__ float s_mean, s_m3, s_var;
  __shared__ float s_kl[16], s_cnt[16];

  float st = 0.f, sm3 = 0.f;
  for (int r = tid; r < M; r += 256) {
    float4 v = rowtab[r];
    st += v.x; sm3 += v.z;
  }
  redf[tid] = st; __syncthreads();
  for (int s = 128; s > 0; s >>= 1) { if (tid < s) redf[tid] += redf[tid + s]; __syncthreads(); }
  if (tid == 0) s_mean = redf[0] / (float)M;
  __syncthreads();
  redf[tid] = sm3; __syncthreads();
  for (int s = 128; s > 0; s >>= 1) { if (tid < s) redf[tid] += redf[tid + s]; __syncthreads(); }
  if (tid == 0) s_m3 = redf[0] / (float)M;
  __syncthreads();

  const float mean = s_mean;
  float sv = 0.f;
  for (int r = tid; r < M; r += 256) { float d = rowtab[r].x - mean; sv = fmaf(d, d, sv); }
  __syncthreads();
  redf[tid] = sv; __syncthreads();
  for (int s = 128; s > 0; s >>= 1) { if (tid < s) redf[tid] += redf[tid + s]; __syncthreads(); }
  if (tid == 0) s_var = redf[0];
  __syncthreads();

  const int nb = B < 16 ? B : 16;
  for (int b = 0; b < nb; ++b) {
    float lk = 0.f, lc = 0.f;
    for (int t = tid; t < T; t += 256) {
      int r = b * T + t;
      float mk = mask[r];
      lk = fmaf(rowtab[r].y, mk, lk);
      lc += mk;
    }
    __syncthreads();
    redf[tid] = lk; __syncthreads();
    for (int s = 128; s > 0; s >>= 1) { if (tid < s) redf[tid] += redf[tid + s]; __syncthreads(); }
    if (tid == 0) s_kl[b] = redf[0];
    __syncthreads();
    redf[tid] = lc; __syncthreads();
    for (int s = 128; s > 0; s >>= 1) { if (tid < s) redf[tid] += redf[tid + s]; __syncthreads(); }
    if (tid == 0) s_cnt[b] = redf[0];
    __syncthreads();
  }

  if (tid == 0) {
    float rmean = 0.f;
    for (int b = 0; b < B; ++b) rmean += rewards[b];
    rmean /= (float)B;
    float rv = 0.f;
    for (int b = 0; b < B; ++b) { float d = rewards[b] - rmean; rv += d * d; }
    float rstd = sqrtf(rv / (float)(B > 1 ? B - 1 : 1));

    float loss = 0.f, m4n = 0.f, m4d = 0.f;
    for (int b = 0; b < nb; ++b) {
      float adv  = (rewards[b] - rmean) / (rstd + 1e-8f);
      float cnt  = s_cnt[b];
      float seql = fmaxf(cnt, 1.0f);
      loss += (-adv * cnt + GRPO_BETA * s_kl[b]) / seql;
      m4n += s_kl[b];
      m4d += cnt;
    }
    loss /= (float)B;

    out[0] = loss;
    out[1] = s_mean;
    out[2] = sqrtf(s_var / (float)(M - 1));
    out[3] = s_m3;
    out[4] = m4n / m4d;
  }
}

// ---------------------------------------------------------------------------
extern "C" void kernel_launch(void* const* d_in, const int* in_sizes, int n_in,
                              void* d_out, int out_size, void* d_ws, size_t ws_size,
                              hipStream_t stream)
{
  if (n_in < 6) return;
  const float* A       = (const float*)d_in[0];
  const float* W       = (const float*)d_in[1];
  const float* mask    = (const float*)d_in[2];
  const float* rewards = (const float*)d_in[3];
  const float* rA      = (const float*)d_in[4];
  const float* rW      = (const float*)d_in[5];

  const int M = in_sizes[2];            // B*T
  const int B = in_sizes[3];
  const int T = M / B;
  const int K = in_sizes[0] / M;        // H
  const int V = in_sizes[1] / K;

  // pick NL (vocab sub-tiles per block) so partials fit in ws
  int NL = 1;
  auto need = [&](int nl) -> size_t {
    int nc = (V + BN * nl - 1) / (BN * nl);
    return (size_t)M * nc * 16 + (size_t)M * nc * 8 + (size_t)M * 16;
  };
  while (need(NL) > ws_size && NL < 1024) NL <<= 1;
  const int NC = (V + BN * NL - 1) / (BN * NL);

  float* partP  = (float*)d_ws;                    // M*NC float4
  float* partR  = partP + (size_t)M * NC * 4;      // M*NC float2
  float* rowtab = partR + (size_t)M * NC * 2;      // M float4

  dim3 g1((M + BM - 1) / BM, NC), b1(512);
  mfma_gemm_reduce<true ><<<g1, b1, 0, stream>>>(A,  W,  partP, M, K, V, NC, NL);
  mfma_gemm_reduce<false><<<g1, b1, 0, stream>>>(rA, rW, partR, M, K, V, NC, NL);
  combine_kernel<<<dim3(M), dim3(256), 0, stream>>>(
      (const float4*)partP, (const float2*)partR, rA, rW, (float4*)rowtab, M, K, V, NC);
  final_kernel<<<dim3(1), dim3(256), 0, stream>>>(
      (const float4*)rowtab, mask, rewards, (float*)d_out, M, B, T);
}

// Round 3
// 1723.860 us; speedup vs baseline: 4.0939x; 1.5904x over previous
//
#include <hip/hip_runtime.h>
#include <math.h>

#define GRPO_BETA 0.1f

constexpr int BM = 128;    // rows per block tile
constexpr int BN = 256;    // vocab cols per block tile (chunk width)
constexpr int BK = 32;     // k-slab (one MFMA-K per step)

typedef __attribute__((ext_vector_type(4))) float   f32x4;
typedef __attribute__((ext_vector_type(8))) __bf16  bf16x8;
typedef __attribute__((ext_vector_type(4))) __bf16  bf16x4;

// NaN-safe exp for lse merges: args expected <= 0; fminf(NaN,0)=0.
__device__ __forceinline__ float sexp_fast(float a) { return __expf(fminf(a, 0.f)); }
__device__ __forceinline__ float sexp(float a)      { return expf(fminf(a, 0.f)); }

__device__ __forceinline__ bf16x4 cvt4(float4 v) {
  bf16x4 r;
  r[0] = (__bf16)v.x; r[1] = (__bf16)v.y; r[2] = (__bf16)v.z; r[3] = (__bf16)v.w;
  return r;
}

// ---------------------------------------------------------------------------
// Kernel 1: bf16-MFMA GEMM (logits = A[M,K] x W[V,K]^T), f32 inputs converted
// in-kernel, fused per-row per-256-col-chunk reductions.
// Pipeline: regs hold slab t+1 while MFMA consumes LDS slab t (issue-early /
// write-late); vmcnt drain lands at the barrier AFTER the compute phase.
// 1-D grid, XCD-remapped so the 16 row-tiles sharing a W-slice are
// consecutive on one XCD (W slice = 1 MB -> L2-resident).
// grid = (gx*NC), block = 512 (8 waves: 2 M x 4 N, wave tile 64x64)
// ---------------------------------------------------------------------------
template <bool POLICY>
__global__ __launch_bounds__(512)
void mfma_gemm_reduce(const float* __restrict__ A,
                      const float* __restrict__ W,
                      float* __restrict__ part,
                      int M, int K, int V, int NC, int NL, int gx)
{
  // LDS bf16 tiles, 64-byte rows, XOR-swizzled: byte = row*64 + (off ^ ((row&3)<<4))
  __shared__ __align__(16) unsigned short lds_a[BM * BK];   // 8 KB
  __shared__ __align__(16) unsigned short lds_w[BN * BK];   // 16 KB
  __shared__ __align__(16) float4 lds_red[BM * 4];          // [row][wn], 8 KB

  const int tid  = threadIdx.x;
  const int lane = tid & 63;
  const int wave = tid >> 6;      // 0..7
  const int wm   = wave >> 2;     // 0..1  (M half)
  const int wn   = wave & 3;      // 0..3  (N quarter)
  const int l15  = lane & 15;
  const int q    = lane >> 4;     // 0..3

  // ---- XCD-aware block remap (bijective when nb % 8 == 0) ----
  const int nb  = gridDim.x;
  const int bid = blockIdx.x;
  int wl = bid;
  if ((nb & 7) == 0) wl = (bid & 7) * (nb >> 3) + (bid >> 3);
  const int bx = wl % gx;
  const int chunk = wl / gx;      // vocab chunk
  const int row0 = bx * BM;

  // ---- staging map: t7 covers k floats [t7*4 .. t7*4+3], tr = row group ----
  const int t7 = tid & 7;
  const int tr = tid >> 3;        // 0..63
  const float* pa[2];
  int la[2];
#pragma unroll
  for (int i = 0; i < 2; ++i) {
    const int r = tr + 64 * i;                       // 0..127
    const int arow = min(row0 + r, M - 1);
    pa[i] = A + (size_t)arow * K + t7 * 4;
    la[i] = r * 64 + ((t7 * 8) ^ ((r & 3) << 4));
  }
  int lw[4];
#pragma unroll
  for (int i = 0; i < 4; ++i) {
    const int c = tr + 64 * i;                       // 0..255
    lw[i] = c * 64 + ((t7 * 8) ^ ((c & 3) << 4));
  }

  // ---- fragment read offsets (swizzled) ----
  int aoff[4], woff[4];
#pragma unroll
  for (int f = 0; f < 4; ++f) {
    const int ra = wm * 64 + f * 16 + l15;
    aoff[f] = ra * 64 + ((q * 16) ^ ((ra & 3) << 4));
    const int rw = wn * 64 + f * 16 + l15;
    woff[f] = rw * 64 + ((q * 16) ^ ((rw & 3) << 4));
  }

  // running per-row records (threads 0..127 own local row = tid)
  float rm = -INFINITY, rse = 0.f, rsum = 0.f;
  int   ridx = 0x7fffffff;

  for (int sub = 0; sub < NL; ++sub) {
    const int v0 = (chunk * NL + sub) * BN;
    if (v0 >= V) break;

    const float* pw[4];
#pragma unroll
    for (int i = 0; i < 4; ++i) {
      const int wrow = min(v0 + tr + 64 * i, V - 1);
      pw[i] = W + (size_t)wrow * K + t7 * 4;
    }

    f32x4 acc[4][4];
#pragma unroll
    for (int i = 0; i < 4; ++i)
#pragma unroll
      for (int j = 0; j < 4; ++j) acc[i][j] = (f32x4){0.f, 0.f, 0.f, 0.f};

    // pipeline prologue: slab 0 into regs
    float4 ar[2], wr[4];
#pragma unroll
    for (int i = 0; i < 2; ++i) ar[i] = *reinterpret_cast<const float4*>(pa[i]);
#pragma unroll
    for (int i = 0; i < 4; ++i) wr[i] = *reinterpret_cast<const float4*>(pw[i]);

    for (int k0 = 0; k0 < K; k0 += BK) {
      __syncthreads();  // prev slab's LDS readers done (drains prefetch vmcnt)
#pragma unroll
      for (int i = 0; i < 2; ++i)
        *reinterpret_cast<bf16x4*>(reinterpret_cast<char*>(lds_a) + la[i]) = cvt4(ar[i]);
#pragma unroll
      for (int i = 0; i < 4; ++i)
        *reinterpret_cast<bf16x4*>(reinterpret_cast<char*>(lds_w) + lw[i]) = cvt4(wr[i]);
      __syncthreads();

      // issue next slab's loads NOW; their wait lands at next barrier A
      if (k0 + BK < K) {
#pragma unroll
        for (int i = 0; i < 2; ++i) ar[i] = *reinterpret_cast<const float4*>(pa[i] + k0 + BK);
#pragma unroll
        for (int i = 0; i < 4; ++i) wr[i] = *reinterpret_cast<const float4*>(pw[i] + k0 + BK);
      }

      bf16x8 afr[4], wfr[4];
#pragma unroll
      for (int f = 0; f < 4; ++f)
        afr[f] = *reinterpret_cast<const bf16x8*>(reinterpret_cast<const char*>(lds_a) + aoff[f]);
#pragma unroll
      for (int f = 0; f < 4; ++f)
        wfr[f] = *reinterpret_cast<const bf16x8*>(reinterpret_cast<const char*>(lds_w) + woff[f]);
#pragma unroll
      for (int fm = 0; fm < 4; ++fm)
#pragma unroll
        for (int fn = 0; fn < 4; ++fn)
          acc[fm][fn] = __builtin_amdgcn_mfma_f32_16x16x32_bf16(
              afr[fm], wfr[fn], acc[fm][fn], 0, 0, 0);
    }

    // ---- fused epilogue: per-row reduction over this 256-col sub-tile ----
    // C/D layout: col = lane&15, row = (lane>>4)*4 + reg  [verified m89/m91]
#pragma unroll
    for (int fm = 0; fm < 4; ++fm) {
#pragma unroll
      for (int reg = 0; reg < 4; ++reg) {
        float lm = -INFINITY; int li = 0x7fffffff; float lsum = 0.f;
#pragma unroll
        for (int fn = 0; fn < 4; ++fn) {
          const int v = v0 + wn * 64 + fn * 16 + l15;
          const float x = acc[fm][fn][reg];
          if (v < V) {
            lsum += x;
            if (x > lm) { lm = x; li = v; }
          }
        }
        float lse = 0.f;
#pragma unroll
        for (int fn = 0; fn < 4; ++fn) {
          const int v = v0 + wn * 64 + fn * 16 + l15;
          if (v < V) lse += __expf(acc[fm][fn][reg] - lm);
        }
#pragma unroll
        for (int d = 1; d < 16; d <<= 1) {
          const float om  = __shfl_xor(lm, d);
          const int   oi  = __shfl_xor(li, d);
          const float ose = __shfl_xor(lse, d);
          const float osm = __shfl_xor(lsum, d);
          const float nm  = fmaxf(lm, om);
          lse = lse * sexp_fast(lm - nm) + ose * sexp_fast(om - nm);
          lsum += osm;
          if (om > lm || (om == lm && oi < li)) li = oi;
          lm = nm;
        }
        if (l15 == 0) {
          const int row = wm * 64 + fm * 16 + q * 4 + reg;
          lds_red[row * 4 + wn] = make_float4(lm, lse, lsum, __int_as_float(li));
        }
      }
    }
    __syncthreads();

    if (tid < BM) {
      float4 p = lds_red[tid * 4];
      float m = p.x, se = p.y, sm = p.z; int idx = __float_as_int(p.w);
#pragma unroll
      for (int j = 1; j < 4; ++j) {
        const float4 t = lds_red[tid * 4 + j];
        const int ti = __float_as_int(t.w);
        const float nm = fmaxf(m, t.x);
        se = se * sexp_fast(m - nm) + t.y * sexp_fast(t.x - nm);
        sm += t.z;
        if (t.x > m || (t.x == m && ti < idx)) idx = ti;
        m = nm;
      }
      const float nm = fmaxf(rm, m);
      rse = rse * sexp_fast(rm - nm) + se * sexp_fast(m - nm);
      rsum += sm;
      if (m > rm || (m == rm && idx < ridx)) ridx = idx;
      rm = nm;
    }
    // next sub's first __syncthreads orders these reads before LDS reuse
  }

  if (tid < BM) {
    const int row = row0 + tid;
    if (row < M) {
      if (POLICY) {
        reinterpret_cast<float4*>(part)[(size_t)row * NC + chunk] =
            make_float4(rm, rse, rsum, __int_as_float(ridx));
      } else {
        reinterpret_cast<float2*>(part)[(size_t)row * NC + chunk] =
            make_float2(rm, rse);
      }
    }
  }
}

// ---------------------------------------------------------------------------
// Kernel 2: per-row combine of chunk partials + gathered ref dot (f32 exact).
// Writes rowtab[row] = {tok_lp, kl, mean_v(log_probs_row), 0}
// grid = (M), block = 256
// ---------------------------------------------------------------------------
__global__ __launch_bounds__(256)
void combine_kernel(const float4* __restrict__ partP,
                    const float2* __restrict__ partR,
                    const float* __restrict__ refA,
                    const float* __restrict__ refW,
                    float4* __restrict__ rowtab,
                    int M, int K, int V, int NC)
{
  const int row = blockIdx.x;
  const int tid = threadIdx.x;

  __shared__ float redf[256];
  __shared__ int   redi[256];
  __shared__ float s_M, s_SE, s_SUM, s_Mr, s_SEr, s_dot;
  __shared__ int   s_idx;

  float m = -INFINITY, se = 0.f, sm = 0.f; int idx = 0x7fffffff;
  for (int i = tid; i < NC; i += 256) {
    float4 p = partP[(size_t)row * NC + i];
    int pi = __float_as_int(p.w);
    float nm = fmaxf(m, p.x);
    se = se * sexp(m - nm) + p.y * sexp(p.x - nm);
    if (p.x > m || (p.x == m && pi < idx)) idx = pi;
    m = nm;
    sm += p.z;
  }
  redf[tid] = m; redi[tid] = idx;
  __syncthreads();
  for (int s = 128; s > 0; s >>= 1) {
    if (tid < s) {
      float om = redf[tid + s]; int oi = redi[tid + s];
      if (om > redf[tid] || (om == redf[tid] && oi < redi[tid])) { redf[tid] = om; redi[tid] = oi; }
    }
    __syncthreads();
  }
  if (tid == 0) { s_M = redf[0]; s_idx = redi[0]; }
  __syncthreads();
  const float Mp = s_M; const int chosen = s_idx;

  float contrib = se * sexp(m - Mp);
  __syncthreads();
  redf[tid] = contrib; __syncthreads();
  for (int s = 128; s > 0; s >>= 1) { if (tid < s) redf[tid] += redf[tid + s]; __syncthreads(); }
  if (tid == 0) s_SE = redf[0];
  __syncthreads();
  redf[tid] = sm; __syncthreads();
  for (int s = 128; s > 0; s >>= 1) { if (tid < s) redf[tid] += redf[tid + s]; __syncthreads(); }
  if (tid == 0) s_SUM = redf[0];
  __syncthreads();

  float mr = -INFINITY, ser = 0.f;
  for (int i = tid; i < NC; i += 256) {
    float2 p = partR[(size_t)row * NC + i];
    float nm = fmaxf(mr, p.x);
    ser = ser * sexp(mr - nm) + p.y * sexp(p.x - nm);
    mr = nm;
  }
  redf[tid] = mr; __syncthreads();
  for (int s = 128; s > 0; s >>= 1) { if (tid < s) redf[tid] = fmaxf(redf[tid], redf[tid + s]); __syncthreads(); }
  if (tid == 0) s_Mr = redf[0];
  __syncthreads();
  const float Mr = s_Mr;
  float contribr = ser * sexp(mr - Mr);
  __syncthreads();
  redf[tid] = contribr; __syncthreads();
  for (int s = 128; s > 0; s >>= 1) { if (tid < s) redf[tid] += redf[tid + s]; __syncthreads(); }
  if (tid == 0) s_SEr = redf[0];
  __syncthreads();

  float dp = 0.f;
  const float* ar = refA + (size_t)row * K;
  const float* wr = refW + (size_t)chosen * K;
  for (int j = tid * 4; j < K; j += 256 * 4) {
    float4 x = *reinterpret_cast<const float4*>(ar + j);
    float4 y = *reinterpret_cast<const float4*>(wr + j);
    dp = fmaf(x.x, y.x, dp);
    dp = fmaf(x.y, y.y, dp);
    dp = fmaf(x.z, y.z, dp);
    dp = fmaf(x.w, y.w, dp);
  }
  __syncthreads();
  redf[tid] = dp; __syncthreads();
  for (int s = 128; s > 0; s >>= 1) { if (tid < s) redf[tid] += redf[tid + s]; __syncthreads(); }
  if (tid == 0) s_dot = redf[0];
  __syncthreads();

  if (tid == 0) {
    float lse     = Mp + logf(s_SE);
    float tok     = Mp - lse;
    float ref_lse = Mr + logf(s_SEr);
    float ref_tok = s_dot - ref_lse;
    float d  = ref_tok - tok;
    float kl = expm1f(d) - d;
    float rm3 = s_SUM / (float)V - lse;
    rowtab[row] = make_float4(tok, kl, rm3, 0.f);
  }
}

// ---------------------------------------------------------------------------
// Kernel 3: final reduction over rows -> 5 scalar outputs. grid=(1), block=256
// ---------------------------------------------------------------------------
__global__ __launch_bounds__(256)
void final_kernel(const float4* __restrict__ rowtab,
                  const float* __restrict__ mask,
                  const float* __restrict__ rewards,
                  float* __restrict__ out,
                  int M, int B, int T)
{
  const int tid = threadIdx.x;
  __shared__ float redf[256];
  __shared__ float s_mean, s_m3, s_var;
  __shared__ float s_kl[16], s_cnt[16];

  float st = 0.f, sm3 = 0.f;
  for (int r = tid; r < M; r += 256) {
    float4 v = rowtab[r];
    st += v.x; sm3 += v.z;
  }
  redf[tid] = st; __syncthreads();
  for (int s = 128; s > 0; s >>= 1) { if (tid < s) redf[tid] += redf[tid + s]; __syncthreads(); }
  if (tid == 0) s_mean = redf[0] / (float)M;
  __syncthreads();
  redf[tid] = sm3; __syncthreads();
  for (int s = 128; s > 0; s >>= 1) { if (tid < s) redf[tid] += redf[tid + s]; __syncthreads(); }
  if (tid == 0) s_m3 = redf[0] / (float)M;
  __syncthreads();

  const float mean = s_mean;
  float sv = 0.f;
  for (int r = tid; r < M; r += 256) { float d = rowtab[r].x - mean; sv = fmaf(d, d, sv); }
  __syncthreads();
  redf[tid] = sv; __syncthreads();
  for (int s = 128; s > 0; s >>= 1) { if (tid < s) redf[tid] += redf[tid + s]; __syncthreads(); }
  if (tid == 0) s_var = redf[0];
  __syncthreads();

  const int nb = B < 16 ? B : 16;
  for (int b = 0; b < nb; ++b) {
    float lk = 0.f, lc = 0.f;
    for (int t = tid; t < T; t += 256) {
      int r = b * T + t;
      float mk = mask[r];
      lk = fmaf(rowtab[r].y, mk, lk);
      lc += mk;
    }
    __syncthreads();
    redf[tid] = lk; __syncthreads();
    for (int s = 128; s > 0; s >>= 1) { if (tid < s) redf[tid] += redf[tid + s]; __syncthreads(); }
    if (tid == 0) s_kl[b] = redf[0];
    __syncthreads();
    redf[tid] = lc; __syncthreads();
    for (int s = 128; s > 0; s >>= 1) { if (tid < s) redf[tid] += redf[tid + s]; __syncthreads(); }
    if (tid == 0) s_cnt[b] = redf[0];
    __syncthreads();
  }

  if (tid == 0) {
    float rmean = 0.f;
    for (int b = 0; b < B; ++b) rmean += rewards[b];
    rmean /= (float)B;
    float rv = 0.f;
    for (int b = 0; b < B; ++b) { float d = rewards[b] - rmean; rv += d * d; }
    float rstd = sqrtf(rv / (float)(B > 1 ? B - 1 : 1));

    float loss = 0.f, m4n = 0.f, m4d = 0.f;
    for (int b = 0; b < nb; ++b) {
      float adv  = (rewards[b] - rmean) / (rstd + 1e-8f);
      float cnt  = s_cnt[b];
      float seql = fmaxf(cnt, 1.0f);
      loss += (-adv * cnt + GRPO_BETA * s_kl[b]) / seql;
      m4n += s_kl[b];
      m4d += cnt;
    }
    loss /= (float)B;

    out[0] = loss;
    out[1] = s_mean;
    out[2] = sqrtf(s_var / (float)(M - 1));
    out[3] = s_m3;
    out[4] = m4n / m4d;
  }
}

// ---------------------------------------------------------------------------
extern "C" void kernel_launch(void* const* d_in, const int* in_sizes, int n_in,
                              void* d_out, int out_size, void* d_ws, size_t ws_size,
                              hipStream_t stream)
{
  if (n_in < 6) return;
  const float* A       = (const float*)d_in[0];
  const float* W       = (const float*)d_in[1];
  const float* mask    = (const float*)d_in[2];
  const float* rewards = (const float*)d_in[3];
  const float* rA      = (const float*)d_in[4];
  const float* rW      = (const float*)d_in[5];

  const int M = in_sizes[2];            // B*T
  const int B = in_sizes[3];
  const int T = M / B;
  const int K = in_sizes[0] / M;        // H
  const int V = in_sizes[1] / K;

  // pick NL (vocab sub-tiles per block) so partials fit in ws
  int NL = 1;
  auto need = [&](int nl) -> size_t {
    int nc = (V + BN * nl - 1) / (BN * nl);
    return (size_t)M * nc * 16 + (size_t)M * nc * 8 + (size_t)M * 16;
  };
  while (need(NL) > ws_size && NL < 1024) NL <<= 1;
  const int NC = (V + BN * NL - 1) / (BN * NL);
  const int gx = (M + BM - 1) / BM;

  float* partP  = (float*)d_ws;                    // M*NC float4
  float* partR  = partP + (size_t)M * NC * 4;      // M*NC float2
  float* rowtab = partR + (size_t)M * NC * 2;      // M float4

  dim3 g1(gx * NC), b1(512);
  mfma_gemm_reduce<true ><<<g1, b1, 0, stream>>>(A,  W,  partP, M, K, V, NC, NL, gx);
  mfma_gemm_reduce<false><<<g1, b1, 0, stream>>>(rA, rW, partR, M, K, V, NC, NL, gx);
  combine_kernel<<<dim3(M), dim3(256), 0, stream>>>(
      (const float4*)partP, (const float2*)partR, rA, rW, (float4*)rowtab, M, K, V, NC);
  final_kernel<<<dim3(1), dim3(256), 0, stream>>>(
      (const float4*)rowtab, mask, rewards, (float*)d_out, M, B, T);
}

// Round 4
// 1163.826 us; speedup vs baseline: 6.0639x; 1.4812x over previous
//
#include <hip/hip_runtime.h>
#include <math.h>

#define GRPO_BETA 0.1f

constexpr int BM = 128;    // rows per block tile
constexpr int BN = 256;    // vocab cols per block tile (chunk width)
constexpr int BK = 32;     // k-slab; LDS rows hold 2 slabs (128B, double-buffered)

typedef __attribute__((ext_vector_type(4))) float   f32x4;
typedef __attribute__((ext_vector_type(8))) __bf16  bf16x8;
typedef __attribute__((ext_vector_type(4))) __bf16  bf16x4;

// NaN-safe exp for lse merges: args expected <= 0; fminf(NaN,0)=0.
__device__ __forceinline__ float sexp_fast(float a) { return __expf(fminf(a, 0.f)); }
__device__ __forceinline__ float sexp(float a)      { return expf(fminf(a, 0.f)); }

__device__ __forceinline__ bf16x4 cvt4(float4 v) {
  bf16x4 r;
  r[0] = (__bf16)v.x; r[1] = (__bf16)v.y; r[2] = (__bf16)v.z; r[3] = (__bf16)v.w;
  return r;
}

// barrier WITHOUT vmcnt drain: LDS writes made visible (lgkmcnt), global
// prefetch loads stay in flight across the barrier (T4-minimum).
__device__ __forceinline__ void bar_lgkm() {
  asm volatile("s_waitcnt lgkmcnt(0)\n\ts_barrier" ::: "memory");
}

// ---------------------------------------------------------------------------
// Kernel 1: bf16-MFMA GEMM (logits = A[M,K] x W[V,K]^T), f32 inputs converted
// in-kernel, fused per-row per-256-col-chunk reductions.
// LDS layout: [row][128B] where byte x of row r lives at r*128 + (x ^ ((r&7)<<4)).
//   - bytes [0,64)   = k-slab with even parity, bytes [64,128) = odd parity
//   - swizzle spreads every row across all 32 banks: staging writes and
//     ds_read_b128 fragment reads are conflict-free (round-2 verified).
// Pipeline per K-step s (ONE lgkm-barrier per step):
//   compute slab s (half s&1) -> stage regs(slab s+1) -> half (s+1)&1
//   -> issue global loads slab s+2 -> bar_lgkm
// grid = (gx*NC) XCD-remapped, block = 512 (8 waves: 2M x 4N, wave tile 64x64)
// ---------------------------------------------------------------------------
template <bool POLICY>
__global__ __launch_bounds__(512, 4)
void mfma_gemm_reduce(const float* __restrict__ A,
                      const float* __restrict__ W,
                      float* __restrict__ part,
                      int M, int K, int V, int NC, int NL, int gx)
{
  __shared__ __align__(16) unsigned short lds_a[BM * 64];   // 16 KB (2 slabs)
  __shared__ __align__(16) unsigned short lds_w[BN * 64];   // 32 KB (2 slabs)
  __shared__ __align__(16) float4 lds_red[BM * 4];          // 8 KB

  const int tid  = threadIdx.x;
  const int lane = tid & 63;
  const int wave = tid >> 6;      // 0..7
  const int wm   = wave >> 2;     // 0..1  (M half)
  const int wn   = wave & 3;      // 0..3  (N quarter)
  const int l15  = lane & 15;
  const int q    = lane >> 4;     // 0..3

  // ---- XCD-aware block remap (bijective when nb % 8 == 0) ----
  const int nb  = gridDim.x;
  int wl = blockIdx.x;
  if ((nb & 7) == 0) wl = (wl & 7) * (nb >> 3) + (wl >> 3);
  const int bx    = wl % gx;
  const int chunk = wl / gx;
  const int row0  = bx * BM;

  // ---- staging map: t7 covers 4 floats at k = t7*4 within a slab ----
  const int t7 = tid & 7;
  const int tr = tid >> 3;        // 0..63 row group
  // LDS write byte offset (slab-parity bit 6 XORed in later)
  const int st0 = tr * 128 + ((t7 * 8) ^ ((tr & 7) << 4));

  int aro[2];
#pragma unroll
  for (int i = 0; i < 2; ++i) aro[i] = min(row0 + tr + 64 * i, M - 1) * K;

  // ---- fragment read byte offsets (slab parity = bit 6; frag f adds 2048) ----
  const int swzr  = ((q * 16) ^ ((l15 & 7) << 4));
  const int aoff0 = (wm * 64 + l15) * 128 + swzr;
  const int woff0 = (wn * 64 + l15) * 128 + swzr;

  // running per-row records (threads 0..127 own local row = tid)
  float rm = -INFINITY, rse = 0.f, rsum = 0.f;
  int   ridx = 0x7fffffff;

  const int NS = K / BK;

  for (int sub = 0; sub < NL; ++sub) {
    const int v0 = (chunk * NL + sub) * BN;
    if (v0 >= V) break;

    int wro[4];
#pragma unroll
    for (int i = 0; i < 4; ++i) wro[i] = min(v0 + tr + 64 * i, V - 1) * K;

    f32x4 acc[4][4];
#pragma unroll
    for (int i = 0; i < 4; ++i)
#pragma unroll
      for (int j = 0; j < 4; ++j) acc[i][j] = (f32x4){0.f, 0.f, 0.f, 0.f};

    // ---- prologue: slab 0 -> LDS half 0; issue slab-1 loads ----
    float4 ar[2], wr[4];
#pragma unroll
    for (int i = 0; i < 2; ++i) ar[i] = *reinterpret_cast<const float4*>(A + aro[i] + t7 * 4);
#pragma unroll
    for (int i = 0; i < 4; ++i) wr[i] = *reinterpret_cast<const float4*>(W + wro[i] + t7 * 4);
#pragma unroll
    for (int i = 0; i < 2; ++i)
      *reinterpret_cast<bf16x4*>(reinterpret_cast<char*>(lds_a) + st0 + i * 8192) = cvt4(ar[i]);
#pragma unroll
    for (int i = 0; i < 4; ++i)
      *reinterpret_cast<bf16x4*>(reinterpret_cast<char*>(lds_w) + st0 + i * 8192) = cvt4(wr[i]);
    if (NS > 1) {
#pragma unroll
      for (int i = 0; i < 2; ++i) ar[i] = *reinterpret_cast<const float4*>(A + aro[i] + BK + t7 * 4);
#pragma unroll
      for (int i = 0; i < 4; ++i) wr[i] = *reinterpret_cast<const float4*>(W + wro[i] + BK + t7 * 4);
    }
    bar_lgkm();

    // ---- main K-loop: 1 barrier per slab ----
    for (int s = 0; s < NS; ++s) {
      const int p = (s & 1) << 6;     // LDS half of slab s

      bf16x8 afr[4];
#pragma unroll
      for (int f = 0; f < 4; ++f)
        afr[f] = *reinterpret_cast<const bf16x8*>(
            reinterpret_cast<const char*>(lds_a) + (aoff0 ^ p) + f * 2048);
      __builtin_amdgcn_s_setprio(1);
#pragma unroll
      for (int fn = 0; fn < 4; ++fn) {
        bf16x8 wfr = *reinterpret_cast<const bf16x8*>(
            reinterpret_cast<const char*>(lds_w) + (woff0 ^ p) + fn * 2048);
#pragma unroll
        for (int fm = 0; fm < 4; ++fm)
          acc[fm][fn] = __builtin_amdgcn_mfma_f32_16x16x32_bf16(
              afr[fm], wfr, acc[fm][fn], 0, 0, 0);
      }
      __builtin_amdgcn_s_setprio(0);

      if (s + 1 < NS) {
        const int p1 = ((s + 1) & 1) << 6;   // stage slab s+1 into other half
#pragma unroll
        for (int i = 0; i < 2; ++i)
          *reinterpret_cast<bf16x4*>(reinterpret_cast<char*>(lds_a) + (st0 ^ p1) + i * 8192) = cvt4(ar[i]);
#pragma unroll
        for (int i = 0; i < 4; ++i)
          *reinterpret_cast<bf16x4*>(reinterpret_cast<char*>(lds_w) + (st0 ^ p1) + i * 8192) = cvt4(wr[i]);
        if (s + 2 < NS) {                    // issue slab s+2 loads (in flight across barrier)
          const int kf = (s + 2) * BK + t7 * 4;
#pragma unroll
          for (int i = 0; i < 2; ++i) ar[i] = *reinterpret_cast<const float4*>(A + aro[i] + kf);
#pragma unroll
          for (int i = 0; i < 4; ++i) wr[i] = *reinterpret_cast<const float4*>(W + wro[i] + kf);
        }
      }
      bar_lgkm();
    }

    // ---- fused epilogue: per-row reduction over this 256-col sub-tile ----
    // C/D layout: col = lane&15, row = (lane>>4)*4 + reg  [verified m89/m91]
#pragma unroll
    for (int fm = 0; fm < 4; ++fm) {
#pragma unroll
      for (int reg = 0; reg < 4; ++reg) {
        float lm = -INFINITY; int li = 0x7fffffff; float lsum = 0.f;
#pragma unroll
        for (int fn = 0; fn < 4; ++fn) {
          const int v = v0 + wn * 64 + fn * 16 + l15;
          const float x = acc[fm][fn][reg];
          if (v < V) {
            lsum += x;
            if (x > lm) { lm = x; li = v; }
          }
        }
        float lse = 0.f;
#pragma unroll
        for (int fn = 0; fn < 4; ++fn) {
          const int v = v0 + wn * 64 + fn * 16 + l15;
          if (v < V) lse += __expf(acc[fm][fn][reg] - lm);
        }
#pragma unroll
        for (int d = 1; d < 16; d <<= 1) {
          const float om  = __shfl_xor(lm, d);
          const int   oi  = __shfl_xor(li, d);
          const float ose = __shfl_xor(lse, d);
          const float osm = __shfl_xor(lsum, d);
          const float nm  = fmaxf(lm, om);
          lse = lse * sexp_fast(lm - nm) + ose * sexp_fast(om - nm);
          lsum += osm;
          if (om > lm || (om == lm && oi < li)) li = oi;
          lm = nm;
        }
        if (l15 == 0) {
          const int row = wm * 64 + fm * 16 + q * 4 + reg;
          lds_red[row * 4 + wn] = make_float4(lm, lse, lsum, __int_as_float(li));
        }
      }
    }
    __syncthreads();

    if (tid < BM) {
      float4 p = lds_red[tid * 4];
      float m = p.x, se = p.y, sm = p.z; int idx = __float_as_int(p.w);
#pragma unroll
      for (int j = 1; j < 4; ++j) {
        const float4 t = lds_red[tid * 4 + j];
        const int ti = __float_as_int(t.w);
        const float nm = fmaxf(m, t.x);
        se = se * sexp_fast(m - nm) + t.y * sexp_fast(t.x - nm);
        sm += t.z;
        if (t.x > m || (t.x == m && ti < idx)) idx = ti;
        m = nm;
      }
      const float nm = fmaxf(rm, m);
      rse = rse * sexp_fast(rm - nm) + se * sexp_fast(m - nm);
      rsum += sm;
      if (m > rm || (m == rm && idx < ridx)) ridx = idx;
      rm = nm;
    }
    __syncthreads();  // lds_red / lds tiles free for next sub
  }

  if (tid < BM) {
    const int row = row0 + tid;
    if (row < M) {
      if (POLICY) {
        reinterpret_cast<float4*>(part)[(size_t)row * NC + chunk] =
            make_float4(rm, rse, rsum, __int_as_float(ridx));
      } else {
        reinterpret_cast<float2*>(part)[(size_t)row * NC + chunk] =
            make_float2(rm, rse);
      }
    }
  }
}

// ---------------------------------------------------------------------------
// Kernel 2: per-row combine of chunk partials + gathered ref dot (f32 exact).
// Writes rowtab[row] = {tok_lp, kl, mean_v(log_probs_row), 0}
// grid = (M), block = 256
// ---------------------------------------------------------------------------
__global__ __launch_bounds__(256)
void combine_kernel(const float4* __restrict__ partP,
                    const float2* __restrict__ partR,
                    const float* __restrict__ refA,
                    const float* __restrict__ refW,
                    float4* __restrict__ rowtab,
                    int M, int K, int V, int NC)
{
  const int row = blockIdx.x;
  const int tid = threadIdx.x;

  __shared__ float redf[256];
  __shared__ int   redi[256];
  __shared__ float s_M, s_SE, s_SUM, s_Mr, s_SEr, s_dot;
  __shared__ int   s_idx;

  float m = -INFINITY, se = 0.f, sm = 0.f; int idx = 0x7fffffff;
  for (int i = tid; i < NC; i += 256) {
    float4 p = partP[(size_t)row * NC + i];
    int pi = __float_as_int(p.w);
    float nm = fmaxf(m, p.x);
    se = se * sexp(m - nm) + p.y * sexp(p.x - nm);
    if (p.x > m || (p.x == m && pi < idx)) idx = pi;
    m = nm;
    sm += p.z;
  }
  redf[tid] = m; redi[tid] = idx;
  __syncthreads();
  for (int s = 128; s > 0; s >>= 1) {
    if (tid < s) {
      float om = redf[tid + s]; int oi = redi[tid + s];
      if (om > redf[tid] || (om == redf[tid] && oi < redi[tid])) { redf[tid] = om; redi[tid] = oi; }
    }
    __syncthreads();
  }
  if (tid == 0) { s_M = redf[0]; s_idx = redi[0]; }
  __syncthreads();
  const float Mp = s_M; const int chosen = s_idx;

  float contrib = se * sexp(m - Mp);
  __syncthreads();
  redf[tid] = contrib; __syncthreads();
  for (int s = 128; s > 0; s >>= 1) { if (tid < s) redf[tid] += redf[tid + s]; __syncthreads(); }
  if (tid == 0) s_SE = redf[0];
  __syncthreads();
  redf[tid] = sm; __syncthreads();
  for (int s = 128; s > 0; s >>= 1) { if (tid < s) redf[tid] += redf[tid + s]; __syncthreads(); }
  if (tid == 0) s_SUM = redf[0];
  __syncthreads();

  float mr = -INFINITY, ser = 0.f;
  for (int i = tid; i < NC; i += 256) {
    float2 p = partR[(size_t)row * NC + i];
    float nm = fmaxf(mr, p.x);
    ser = ser * sexp(mr - nm) + p.y * sexp(p.x - nm);
    mr = nm;
  }
  redf[tid] = mr; __syncthreads();
  for (int s = 128; s > 0; s >>= 1) { if (tid < s) redf[tid] = fmaxf(redf[tid], redf[tid + s]); __syncthreads(); }
  if (tid == 0) s_Mr = redf[0];
  __syncthreads();
  const float Mr = s_Mr;
  float contribr = ser * sexp(mr - Mr);
  __syncthreads();
  redf[tid] = contribr; __syncthreads();
  for (int s = 128; s > 0; s >>= 1) { if (tid < s) redf[tid] += redf[tid + s]; __syncthreads(); }
  if (tid == 0) s_SEr = redf[0];
  __syncthreads();

  float dp = 0.f;
  const float* ar = refA + (size_t)row * K;
  const float* wr = refW + (size_t)chosen * K;
  for (int j = tid * 4; j < K; j += 256 * 4) {
    float4 x = *reinterpret_cast<const float4*>(ar + j);
    float4 y = *reinterpret_cast<const float4*>(wr + j);
    dp = fmaf(x.x, y.x, dp);
    dp = fmaf(x.y, y.y, dp);
    dp = fmaf(x.z, y.z, dp);
    dp = fmaf(x.w, y.w, dp);
  }
  __syncthreads();
  redf[tid] = dp; __syncthreads();
  for (int s = 128; s > 0; s >>= 1) { if (tid < s) redf[tid] += redf[tid + s]; __syncthreads(); }
  if (tid == 0) s_dot = redf[0];
  __syncthreads();

  if (tid == 0) {
    float lse     = Mp + logf(s_SE);
    float tok     = Mp - lse;
    float ref_lse = Mr + logf(s_SEr);
    float ref_tok = s_dot - ref_lse;
    float d  = ref_tok - tok;
    float kl = expm1f(d) - d;
    float rm3 = s_SUM / (float)V - lse;
    rowtab[row] = make_float4(tok, kl, rm3, 0.f);
  }
}

// ---------------------------------------------------------------------------
// Kernel 3: final reduction over rows -> 5 scalar outputs. grid=(1), block=256
// ---------------------------------------------------------------------------
__global__ __launch_bounds__(256)
void final_kernel(const float4* __restrict__ rowtab,
                  const float* __restrict__ mask,
                  const float* __restrict__ rewards,
                  float* __restrict__ out,
                  int M, int B, int T)
{
  const int tid = threadIdx.x;
  __shared__ float redf[256];
  __shared__ float s_mean, s_m3, s_var;
  __shared__ float s_kl[16], s_cnt[16];

  float st = 0.f, sm3 = 0.f;
  for (int r = tid; r < M; r += 256) {
    float4 v = rowtab[r];
    st += v.x; sm3 += v.z;
  }
  redf[tid] = st; __syncthreads();
  for (int s = 128; s > 0; s >>= 1) { if (tid < s) redf[tid] += redf[tid + s]; __syncthreads(); }
  if (tid == 0) s_mean = redf[0] / (float)M;
  __syncthreads();
  redf[tid] = sm3; __syncthreads();
  for (int s = 128; s > 0; s >>= 1) { if (tid < s) redf[tid] += redf[tid + s]; __syncthreads(); }
  if (tid == 0) s_m3 = redf[0] / (float)M;
  __syncthreads();

  const float mean = s_mean;
  float sv = 0.f;
  for (int r = tid; r < M; r += 256) { float d = rowtab[r].x - mean; sv = fmaf(d, d, sv); }
  __syncthreads();
  redf[tid] = sv; __syncthreads();
  for (int s = 128; s > 0; s >>= 1) { if (tid < s) redf[tid] += redf[tid + s]; __syncthreads(); }
  if (tid == 0) s_var = redf[0];
  __syncthreads();

  const int nb = B < 16 ? B : 16;
  for (int b = 0; b < nb; ++b) {
    float lk = 0.f, lc = 0.f;
    for (int t = tid; t < T; t += 256) {
      int r = b * T + t;
      float mk = mask[r];
      lk = fmaf(rowtab[r].y, mk, lk);
      lc += mk;
    }
    __syncthreads();
    redf[tid] = lk; __syncthreads();
    for (int s = 128; s > 0; s >>= 1) { if (tid < s) redf[tid] += redf[tid + s]; __syncthreads(); }
    if (tid == 0) s_kl[b] = redf[0];
    __syncthreads();
    redf[tid] = lc; __syncthreads();
    for (int s = 128; s > 0; s >>= 1) { if (tid < s) redf[tid] += redf[tid + s]; __syncthreads(); }
    if (tid == 0) s_cnt[b] = redf[0];
    __syncthreads();
  }

  if (tid == 0) {
    float rmean = 0.f;
    for (int b = 0; b < B; ++b) rmean += rewards[b];
    rmean /= (float)B;
    float rv = 0.f;
    for (int b = 0; b < B; ++b) { float d = rewards[b] - rmean; rv += d * d; }
    float rstd = sqrtf(rv / (float)(B > 1 ? B - 1 : 1));

    float loss = 0.f, m4n = 0.f, m4d = 0.f;
    for (int b = 0; b < nb; ++b) {
      float adv  = (rewards[b] - rmean) / (rstd + 1e-8f);
      float cnt  = s_cnt[b];
      float seql = fmaxf(cnt, 1.0f);
      loss += (-adv * cnt + GRPO_BETA * s_kl[b]) / seql;
      m4n += s_kl[b];
      m4d += cnt;
    }
    loss /= (float)B;

    out[0] = loss;
    out[1] = s_mean;
    out[2] = sqrtf(s_var / (float)(M - 1));
    out[3] = s_m3;
    out[4] = m4n / m4d;
  }
}

// ---------------------------------------------------------------------------
extern "C" void kernel_launch(void* const* d_in, const int* in_sizes, int n_in,
                              void* d_out, int out_size, void* d_ws, size_t ws_size,
                              hipStream_t stream)
{
  if (n_in < 6) return;
  const float* A       = (const float*)d_in[0];
  const float* W       = (const float*)d_in[1];
  const float* mask    = (const float*)d_in[2];
  const float* rewards = (const float*)d_in[3];
  const float* rA      = (const float*)d_in[4];
  const float* rW      = (const float*)d_in[5];

  const int M = in_sizes[2];            // B*T
  const int B = in_sizes[3];
  const int T = M / B;
  const int K = in_sizes[0] / M;        // H
  const int V = in_sizes[1] / K;

  // pick NL (vocab sub-tiles per block) so partials fit in ws
  int NL = 1;
  auto need = [&](int nl) -> size_t {
    int nc = (V + BN * nl - 1) / (BN * nl);
    return (size_t)M * nc * 16 + (size_t)M * nc * 8 + (size_t)M * 16;
  };
  while (need(NL) > ws_size && NL < 1024) NL <<= 1;
  const int NC = (V + BN * NL - 1) / (BN * NL);
  const int gx = (M + BM - 1) / BM;

  float* partP  = (float*)d_ws;                    // M*NC float4
  float* partR  = partP + (size_t)M * NC * 4;      // M*NC float2
  float* rowtab = partR + (size_t)M * NC * 2;      // M float4

  dim3 g1(gx * NC), b1(512);
  mfma_gemm_reduce<true ><<<g1, b1, 0, stream>>>(A,  W,  partP, M, K, V, NC, NL, gx);
  mfma_gemm_reduce<false><<<g1, b1, 0, stream>>>(rA, rW, partR, M, K, V, NC, NL, gx);
  combine_kernel<<<dim3(M), dim3(256), 0, stream>>>(
      (const float4*)partP, (const float2*)partR, rA, rW, (float4*)rowtab, M, K, V, NC);
  final_kernel<<<dim3(1), dim3(256), 0, stream>>>(
      (const float4*)rowtab, mask, rewards, (float*)d_out, M, B, T);
}